// Round 6
// baseline (534.279 us; speedup 1.0000x reference)
//
#include <hip/hip_runtime.h>

// LSTM decoder: B=1024, S=256, H=128, O=7, T=512
// gates = h @ (W_ih+W_hh).T + (b_ih+b_hh); c'=sig(f)c+sig(i)tanh(g);
// h'=sig(o)tanh(c'); pred = h' @ W_out.T + b_out
//
// Round 6: round-5 structure (in-register gate select, 1 barrier/step,
// 128-VGPR footprint) but RB=2 and 512 blocks -> TWO independent blocks
// per CU (16 waves/CU). Independent barriers drift anti-phase, so each
// block's serial chain (LDS read -> MFMA chain -> transcendental chain ->
// write -> barrier) hides the other's. launch_bounds(512,4) pins the
// allocator at the 128-VGPR cap that round 5 demonstrably fits.

#define HH   128
#define SSEQ 256
#define TT   512
#define OO   7
#define RB   2
#define HSTR 136   // h_lds row stride in shorts (272B = 4-bank skew)

typedef __attribute__((ext_vector_type(8))) short short8;
typedef __attribute__((ext_vector_type(4))) float f32x4;

__device__ __forceinline__ unsigned short f2bf(float x) {
    union { float f; unsigned u; } v; v.f = x;
    return (unsigned short)((v.u + 0x7FFF + ((v.u >> 16) & 1)) >> 16); // RNE
}
__device__ __forceinline__ float sigmoidf_(float x) {
    return __builtin_amdgcn_rcpf(1.f + __expf(-x));
}
__device__ __forceinline__ float tanhf_(float x) {
    return 1.f - 2.f * __builtin_amdgcn_rcpf(__expf(2.f * x) + 1.f);
}

__global__ void __launch_bounds__(512, 4)
lstm_decoder_kernel(const float* __restrict__ ctx,
                    const float* __restrict__ Wih,
                    const float* __restrict__ Whh,
                    const float* __restrict__ bih,
                    const float* __restrict__ bhh,
                    const float* __restrict__ Wout,
                    const float* __restrict__ bout,
                    float* __restrict__ out) {
    __shared__ __align__(16) unsigned short h_lds[2][RB * HSTR];

    const int tid  = threadIdx.x;
    const int lane = tid & 63;
    const int wave = tid >> 6;
    const int rowBase = blockIdx.x * RB;

    const int lo  = lane & 15;
    const int hi  = lane >> 4;       // 0..3
    const int col = wave * 16 + lo;  // this lane's gate/h column (0..127)
    const int arw = lo & 1;          // A-tile real row (2 rows replicated to 16)
    const int erow = hi & 1;         // elementwise row (duplicated across hi pairs)

    // folded biases for this lane's column
    const float bi  = bih[col]          + bhh[col];
    const float bf_ = bih[HH + col]     + bhh[HH + col];
    const float bg  = bih[2 * HH + col] + bhh[2 * HH + col];
    const float bo  = bih[3 * HH + col] + bhh[3 * HH + col];
    const float bo_pred = (lo < OO) ? bout[lo] : 0.f;

    // W fragments (B-operand): wave w, gate g -> n = g*128 + w*16 + lo,
    // lane holds W[n][k0..k0+7], k0 = kt*32 + hi*8
    short8 wfrag[4][4];
#pragma unroll
    for (int g = 0; g < 4; ++g) {
        const int n = g * HH + wave * 16 + lo;
#pragma unroll
        for (int kt = 0; kt < 4; ++kt) {
            const int k0 = kt * 32 + hi * 8;
            const float* p1 = Wih + (size_t)n * HH + k0;
            const float* p2 = Whh + (size_t)n * HH + k0;
            short8 w;
#pragma unroll
            for (int j = 0; j < 8; ++j) w[j] = (short)f2bf(p1[j] + p2[j]);
            wfrag[g][kt] = w;
        }
    }

    // pred B-fragments on wave 0 (W_out rows = output cols, zero-padded to 16)
    short8 wpred[4];
    if (wave == 0) {
#pragma unroll
        for (int kt = 0; kt < 4; ++kt) {
            const int k0 = kt * 32 + hi * 8;
            short8 w;
#pragma unroll
            for (int j = 0; j < 8; ++j)
                w[j] = (lo < OO) ? (short)f2bf(Wout[(size_t)lo * HH + k0 + j]) : (short)0;
            wpred[kt] = w;
        }
    }

    // h0 = context_seq[:, S-1, :]: lanes hi<RB own (row hi, col)
    if (hi < RB) {
        const float v = ctx[(size_t)(rowBase + hi) * SSEQ * HH + (size_t)(SSEQ - 1) * HH + col];
        h_lds[0][hi * HSTR + col] = f2bf(v);
    }
    float c_st = 0.f;   // cell state for (row erow, col) — duplicated across hi pairs
    __syncthreads();

    for (int it = 0; it <= TT; ++it) {
        const int cur = it & 1;

        // A fragments: lane holds h[arw][k0..k0+7], k0 = kt*32 + hi*8
        const int abase = arw * HSTR + hi * 8;
        short8 afrag[4];
#pragma unroll
        for (int kt = 0; kt < 4; ++kt)
            afrag[kt] = *(const short8*)&h_lds[cur][abase + kt * 32];

        // pred = h_it @ Wout.T on wave 0 (h_it -> output step it-1)
        if (wave == 0) {
            f32x4 accp = {0.f, 0.f, 0.f, 0.f};
#pragma unroll
            for (int kt = 0; kt < 4; ++kt)
                accp = __builtin_amdgcn_mfma_f32_16x16x32_bf16(afrag[kt], wpred[kt], accp, 0, 0, 0);
            if (it > 0 && hi == 0 && lo < OO) {
#pragma unroll
                for (int r = 0; r < RB; ++r)
                    out[(size_t)(rowBase + r) * TT * OO + (size_t)(it - 1) * OO + lo] =
                        accp[r] + bo_pred;
            }
        }

        if (it == TT) break;

        // gate MFMAs: 4 gate tiles x 4 K-tiles
        f32x4 acc0 = {0.f, 0.f, 0.f, 0.f};
        f32x4 acc1 = {0.f, 0.f, 0.f, 0.f};
        f32x4 acc2 = {0.f, 0.f, 0.f, 0.f};
        f32x4 acc3 = {0.f, 0.f, 0.f, 0.f};
#pragma unroll
        for (int kt = 0; kt < 4; ++kt) {
            acc0 = __builtin_amdgcn_mfma_f32_16x16x32_bf16(afrag[kt], wfrag[0][kt], acc0, 0, 0, 0);
            acc1 = __builtin_amdgcn_mfma_f32_16x16x32_bf16(afrag[kt], wfrag[1][kt], acc1, 0, 0, 0);
            acc2 = __builtin_amdgcn_mfma_f32_16x16x32_bf16(afrag[kt], wfrag[2][kt], acc2, 0, 0, 0);
            acc3 = __builtin_amdgcn_mfma_f32_16x16x32_bf16(afrag[kt], wfrag[3][kt], acc3, 0, 0, 0);
        }

        // C row = 4*hi + reg; A row m holds real row m&1 -> reg r at ANY hi is
        // the gate for real row r (r<RB). Select reg r = erow in-register.
        const float gi = erow ? acc0[1] : acc0[0];
        const float gf = erow ? acc1[1] : acc1[0];
        const float gg = erow ? acc2[1] : acc2[0];
        const float go = erow ? acc3[1] : acc3[0];

        const float si_ = sigmoidf_(gi + bi);
        const float sf_ = sigmoidf_(gf + bf_);
        const float so_ = sigmoidf_(go + bo);
        const float tg  = tanhf_(gg + bg);
        c_st = sf_ * c_st + si_ * tg;
        const float hnew = so_ * tanhf_(c_st);

        if (hi < RB)
            h_lds[cur ^ 1][hi * HSTR + col] = f2bf(hnew);
        __syncthreads();
    }
}

extern "C" void kernel_launch(void* const* d_in, const int* in_sizes, int n_in,
                              void* d_out, int out_size, void* d_ws, size_t ws_size,
                              hipStream_t stream) {
    const float* ctx  = (const float*)d_in[0];
    const float* Wih  = (const float*)d_in[1];
    const float* Whh  = (const float*)d_in[2];
    const float* bih  = (const float*)d_in[3];
    const float* bhh  = (const float*)d_in[4];
    const float* Wout = (const float*)d_in[5];
    const float* bout = (const float*)d_in[6];
    float* out = (float*)d_out;

    lstm_decoder_kernel<<<dim3(1024 / RB), dim3(512), 0, stream>>>(
        ctx, Wih, Whh, bih, bhh, Wout, bout, out);
}

// Round 7
// 325.159 us; speedup vs baseline: 1.6431x; 1.6431x over previous
//
#include <hip/hip_runtime.h>

// LSTM decoder: B=1024, S=256, H=128, O=7, T=512
// gates = h @ (W_ih+W_hh).T + (b_ih+b_hh); c'=sig(f)c+sig(i)tanh(g);
// h'=sig(o)tanh(c'); pred = h' @ W_out.T + b_out
//
// Round 7 = round 5 (344us: 256 blocks x 512 thr, RB=4, in-register gate
// select, 1 barrier/step, 128 VGPR) + two targeted fixes:
//  (a) preds go to an LDS ring (ds_write), flushed to global every 32 steps
//      by all threads with coalesced stores -> the implicit s_waitcnt
//      vmcnt(0) before s_barrier no longer costs a store round-trip on
//      wave 0's chain EVERY step (the round-1/5 hidden serial cost).
//  (b) HSTR 136->144: A-frag start bank 8r+4hi -> max 2-way (free),
//      was 4(r+hi) -> 4-way (SQ_LDS_BANK_CONFLICT 1.89e7).

#define HH   128
#define SSEQ 256
#define TT   512
#define OO   7
#define RB   4
#define HSTR 144   // h_lds row stride in shorts (288B = 8-bank skew, 16B aligned)

typedef __attribute__((ext_vector_type(8))) short short8;
typedef __attribute__((ext_vector_type(4))) float f32x4;

__device__ __forceinline__ unsigned short f2bf(float x) {
    union { float f; unsigned u; } v; v.f = x;
    return (unsigned short)((v.u + 0x7FFF + ((v.u >> 16) & 1)) >> 16); // RNE
}
__device__ __forceinline__ float sigmoidf_(float x) {
    return __builtin_amdgcn_rcpf(1.f + __expf(-x));
}
__device__ __forceinline__ float tanhf_(float x) {
    return 1.f - 2.f * __builtin_amdgcn_rcpf(__expf(2.f * x) + 1.f);
}

__global__ void __launch_bounds__(512, 2)
lstm_decoder_kernel(const float* __restrict__ ctx,
                    const float* __restrict__ Wih,
                    const float* __restrict__ Whh,
                    const float* __restrict__ bih,
                    const float* __restrict__ bhh,
                    const float* __restrict__ Wout,
                    const float* __restrict__ bout,
                    float* __restrict__ out) {
    __shared__ __align__(16) unsigned short h_lds[2][RB * HSTR];
    // pred ring: [buf][slot][row][col(pad 8)]; step s -> buf (s>>5)&1, slot s&31
    __shared__ __align__(16) float pred_lds[2][32][RB][8];

    const int tid  = threadIdx.x;
    const int lane = tid & 63;
    const int wave = tid >> 6;
    const int rowBase = blockIdx.x * RB;

    const int lo  = lane & 15;
    const int hi  = lane >> 4;       // 0..3: this lane's batch row AND k-slice
    const int col = wave * 16 + lo;  // this lane's gate/h column (0..127)
    const int arw = lo & 3;          // A-tile real row (rows replicated to 16)

    // folded biases for this lane's column
    const float bi  = bih[col]          + bhh[col];
    const float bf_ = bih[HH + col]     + bhh[HH + col];
    const float bg  = bih[2 * HH + col] + bhh[2 * HH + col];
    const float bo  = bih[3 * HH + col] + bhh[3 * HH + col];
    const float bo_pred = (lo < OO) ? bout[lo] : 0.f;

    // W fragments (B-operand): wave w, gate g -> n = g*128 + w*16 + lo,
    // lane holds W[n][k0..k0+7], k0 = kt*32 + hi*8
    short8 wfrag[4][4];
#pragma unroll
    for (int g = 0; g < 4; ++g) {
        const int n = g * HH + wave * 16 + lo;
#pragma unroll
        for (int kt = 0; kt < 4; ++kt) {
            const int k0 = kt * 32 + hi * 8;
            const float* p1 = Wih + (size_t)n * HH + k0;
            const float* p2 = Whh + (size_t)n * HH + k0;
            short8 w;
#pragma unroll
            for (int j = 0; j < 8; ++j) w[j] = (short)f2bf(p1[j] + p2[j]);
            wfrag[g][kt] = w;
        }
    }

    // pred B-fragments on wave 0 (W_out rows = output cols, zero-padded to 16)
    short8 wpred[4];
    if (wave == 0) {
#pragma unroll
        for (int kt = 0; kt < 4; ++kt) {
            const int k0 = kt * 32 + hi * 8;
            short8 w;
#pragma unroll
            for (int j = 0; j < 8; ++j)
                w[j] = (lo < OO) ? (short)f2bf(Wout[(size_t)lo * HH + k0 + j]) : (short)0;
            wpred[kt] = w;
        }
    }

    // h0 = context_seq[:, S-1, :]: lane (hi, col) owns (row hi, col)
    {
        const float v = ctx[(size_t)(rowBase + hi) * SSEQ * HH + (size_t)(SSEQ - 1) * HH + col];
        h_lds[0][hi * HSTR + col] = f2bf(v);
    }
    float c_st = 0.f;   // cell state for (row hi, col)
    __syncthreads();

    for (int it = 0; it <= TT; ++it) {
        const int cur = it & 1;

        // A fragments: lane holds h[arw][k0..k0+7], k0 = kt*32 + hi*8
        const int abase = arw * HSTR + hi * 8;
        short8 afrag[4];
#pragma unroll
        for (int kt = 0; kt < 4; ++kt)
            afrag[kt] = *(const short8*)&h_lds[cur][abase + kt * 32];

        // Coalesced flush of a completed pred buffer (steps s0..s0+31).
        // Buffer finished its last ds_write during iteration s0+32; the
        // barrier at end of s0+32 makes it visible; flush at it==s0+33.
        // Stores issued here overlap this step's MFMA/VALU work; the vmcnt
        // drain at this iteration's barrier is paid once per 32 steps.
        if (it >= 33 && ((it - 33) & 31) == 0) {
            const int s0   = it - 33;
            const int bufb = (s0 >> 5) & 1;
            for (int e = tid; e < 32 * RB * OO; e += 512) {
                const int r  = e / (32 * OO);
                const int re = e - r * (32 * OO);
                const int sl = re / OO;
                const int c  = re - sl * OO;
                out[(size_t)(rowBase + r) * TT * OO + (size_t)(s0 + sl) * OO + c] =
                    pred_lds[bufb][sl][r][c];
            }
        }

        // pred = h_it @ Wout.T on wave 0 (h_it -> output step it-1) -> LDS ring
        if (wave == 0) {
            f32x4 accp = {0.f, 0.f, 0.f, 0.f};
#pragma unroll
            for (int kt = 0; kt < 4; ++kt)
                accp = __builtin_amdgcn_mfma_f32_16x16x32_bf16(afrag[kt], wpred[kt], accp, 0, 0, 0);
            if (it > 0 && hi == 0 && lo < OO) {
                const int s    = it - 1;
                const int bufw = (s >> 5) & 1;
                const int slot = s & 31;
#pragma unroll
                for (int r = 0; r < RB; ++r)
                    pred_lds[bufw][slot][r][lo] = accp[r] + bo_pred;
            }
        }

        if (it == TT) break;

        // gate MFMAs: 4 gate tiles x 4 K-tiles
        f32x4 acc0 = {0.f, 0.f, 0.f, 0.f};
        f32x4 acc1 = {0.f, 0.f, 0.f, 0.f};
        f32x4 acc2 = {0.f, 0.f, 0.f, 0.f};
        f32x4 acc3 = {0.f, 0.f, 0.f, 0.f};
#pragma unroll
        for (int kt = 0; kt < 4; ++kt) {
            acc0 = __builtin_amdgcn_mfma_f32_16x16x32_bf16(afrag[kt], wfrag[0][kt], acc0, 0, 0, 0);
            acc1 = __builtin_amdgcn_mfma_f32_16x16x32_bf16(afrag[kt], wfrag[1][kt], acc1, 0, 0, 0);
            acc2 = __builtin_amdgcn_mfma_f32_16x16x32_bf16(afrag[kt], wfrag[2][kt], acc2, 0, 0, 0);
            acc3 = __builtin_amdgcn_mfma_f32_16x16x32_bf16(afrag[kt], wfrag[3][kt], acc3, 0, 0, 0);
        }

        // C row = 4*hi + reg; A row m holds real row m&3 -> reg r at ANY hi is
        // the gate for real row r. Select reg r = hi in-register (no LDS).
        const bool m1 = (hi == 1), m2 = (hi == 2), m3 = (hi == 3);
        const float gi = m3 ? acc0[3] : m2 ? acc0[2] : m1 ? acc0[1] : acc0[0];
        const float gf = m3 ? acc1[3] : m2 ? acc1[2] : m1 ? acc1[1] : acc1[0];
        const float gg = m3 ? acc2[3] : m2 ? acc2[2] : m1 ? acc2[1] : acc2[0];
        const float go = m3 ? acc3[3] : m2 ? acc3[2] : m1 ? acc3[1] : acc3[0];

        const float si_ = sigmoidf_(gi + bi);
        const float sf_ = sigmoidf_(gf + bf_);
        const float so_ = sigmoidf_(go + bo);
        const float tg  = tanhf_(gg + bg);
        c_st = sf_ * c_st + si_ * tg;
        const float hnew = so_ * tanhf_(c_st);

        h_lds[cur ^ 1][hi * HSTR + col] = f2bf(hnew);
        __syncthreads();
    }

    // epilogue: flush remaining steps 480..511 (written during its 481..512;
    // last write at it=512 needs one barrier before reading)
    __syncthreads();
    {
        const int s0   = TT - 32;            // 480
        const int bufb = (s0 >> 5) & 1;
        for (int e = tid; e < 32 * RB * OO; e += 512) {
            const int r  = e / (32 * OO);
            const int re = e - r * (32 * OO);
            const int sl = re / OO;
            const int c  = re - sl * OO;
            out[(size_t)(rowBase + r) * TT * OO + (size_t)(s0 + sl) * OO + c] =
                pred_lds[bufb][sl][r][c];
        }
    }
}

extern "C" void kernel_launch(void* const* d_in, const int* in_sizes, int n_in,
                              void* d_out, int out_size, void* d_ws, size_t ws_size,
                              hipStream_t stream) {
    const float* ctx  = (const float*)d_in[0];
    const float* Wih  = (const float*)d_in[1];
    const float* Whh  = (const float*)d_in[2];
    const float* bih  = (const float*)d_in[3];
    const float* bhh  = (const float*)d_in[4];
    const float* Wout = (const float*)d_in[5];
    const float* bout = (const float*)d_in[6];
    float* out = (float*)d_out;

    lstm_decoder_kernel<<<dim3(1024 / RB), dim3(512), 0, stream>>>(
        ctx, Wih, Whh, bih, bhh, Wout, bout, out);
}